// Round 5
// baseline (1171.700 us; speedup 1.0000x reference)
//
#include <hip/hip_runtime.h>
#include <hip/hip_bf16.h>

// MoEReadout round 9: TILE=128 atoms, stream BOTH W and X through LDS.
//  - k_gather packs X (gathered by bucket slot) as bf16 Xbf[slot][512].
//  - k_moe_v2: depth-3 chunk pipeline (r8-proven single-barrier scheme) over
//    a 24-chunk stream per (expert,j): 16x{W1 16KB + X 8KB} + 8x{W2 16KB}.
//    Per-lane inverse-swizzled DMA sources -> linear LDS dest, conflict-free
//    ds_read_b128 (2-way max). Wave tile 64x64 (acc 4x4): 8 reads / 16 MFMA.
//  - hs [128][256] XOR-swizzled (slot ^= row&7). setprio(1) around MFMA.
//  - ws_size guard: if workspace can't hold Xbf (~105MB), fall back to the
//    round-8 kernel (k_moe_v1, packed+swizzled weights) - no regression.

typedef __attribute__((ext_vector_type(8))) short short8;   // 8 x bf16
typedef __attribute__((ext_vector_type(4))) float f32x4;    // MFMA acc / 16B load

#define IN_F 512
#define HID  512
#define OUT_F 256

#define WAIT_LGKM0 asm volatile("s_waitcnt lgkmcnt(0)" ::: "memory")
#define WAIT_VM3   asm volatile("s_waitcnt vmcnt(3)"   ::: "memory")
#define WAIT_VM2   asm volatile("s_waitcnt vmcnt(2)"   ::: "memory")
#define WAIT_VM0   asm volatile("s_waitcnt vmcnt(0)"   ::: "memory")

__device__ inline unsigned short f2bf(float f) {
    __hip_bfloat16 h = __float2bfloat16(f);
    return *reinterpret_cast<unsigned short*>(&h);
}

__device__ __forceinline__ void dma16(const unsigned short* g, unsigned short* l) {
    __builtin_amdgcn_global_load_lds(
        (const __attribute__((address_space(1))) unsigned int*)(unsigned long long)(const void*)g,
        (__attribute__((address_space(3))) unsigned int*)(unsigned int)(unsigned long long)(void*)l,
        16, 0, 0);
}

// ---------- prep: weight cvt (mode 0 plain / 1 packed+swz) + state init ----------
__global__ void k_prep(const float* __restrict__ rW1, const float* __restrict__ sW1,
                       const float* __restrict__ rW2, const float* __restrict__ sW2,
                       unsigned short* __restrict__ w1bf, unsigned short* __restrict__ w2bf,
                       int* __restrict__ counts, int* __restrict__ cursors,
                       int* __restrict__ idxl, int* __restrict__ tile_pair,
                       int CAP, int TMAX, int mode) {
    int i = blockIdx.x * 256 + threadIdx.x;
    if (i < 8 * 512 * 512) {
        float v;
        if (mode == 0) {
            int e = i >> 18, off = i & ((1 << 18) - 1);
            v = (e < 6) ? rW1[(size_t)e * 262144 + off]
                        : sW1[(size_t)(e - 6) * 262144 + off];
        } else {
            int low3 = i & 7, sw = (i >> 3) & 3, row = (i >> 5) & 255;
            int kq = (i >> 13) & 15, j = (i >> 17) & 1, ex = i >> 18;
            int col = ((sw ^ ((row >> 1) & 3)) << 3) + low3;
            int hrow = j * 256 + row, kcol = kq * 32 + col;
            v = (ex < 6) ? rW1[((size_t)ex * 512 + hrow) * 512 + kcol]
                         : sW1[((size_t)(ex - 6) * 512 + hrow) * 512 + kcol];
        }
        w1bf[i] = f2bf(v);
    }
    if (i < 8 * 256 * 512) {
        float v;
        if (mode == 0) {
            int e = i >> 17, off = i & ((1 << 17) - 1);
            v = (e < 6) ? rW2[(size_t)e * 131072 + off]
                        : sW2[(size_t)(e - 6) * 131072 + off];
        } else {
            int low3 = i & 7, sw = (i >> 3) & 3, row = (i >> 5) & 255;
            int kq = (i >> 13) & 7, j = (i >> 16) & 1, ex = i >> 17;
            int col = ((sw ^ ((row >> 1) & 3)) << 3) + low3;
            int kcol = j * 256 + kq * 32 + col;
            v = (ex < 6) ? rW2[((size_t)ex * 256 + row) * 512 + kcol]
                         : sW2[((size_t)(ex - 6) * 256 + row) * 512 + kcol];
        }
        w2bf[i] = f2bf(v);
    }
    if (i < 16) { counts[i] = 0; cursors[i] = 0; }
    if (i < TMAX) tile_pair[i] = -1;
    if (i < CAP) idxl[i] = -1;
}

// ---------- router: top-2 -> pair id + gates ----------
__global__ void k_router(const int* __restrict__ species, const float* __restrict__ emb,
                         const float* __restrict__ Wr,
                         int* __restrict__ pid, float* __restrict__ gA, float* __restrict__ gB,
                         int* __restrict__ counts, int N) {
    __shared__ int lcnt[16];
    int tid = threadIdx.x;
    if (tid < 16) lcnt[tid] = 0;
    __syncthreads();
    int i = blockIdx.x * 256 + tid;
    if (i < N) {
        int z = species[i];
        float u[16];
#pragma unroll
        for (int k = 0; k < 16; ++k) {
            float v = emb[z * 16 + k];
            u[k] = v / (1.f + __expf(-v));
        }
        float s[6];
        float mx = -1e30f;
#pragma unroll
        for (int e = 0; e < 6; ++e) {
            float a = 0.f;
#pragma unroll
            for (int k = 0; k < 16; ++k) a += u[k] * Wr[e * 16 + k];
            s[e] = a;
            mx = fmaxf(mx, a);
        }
        float sum = 0.f;
#pragma unroll
        for (int e = 0; e < 6; ++e) { s[e] = __expf(s[e] - mx); sum += s[e]; }
        float inv = 1.f / sum;
        int i0 = 0;
#pragma unroll
        for (int e = 1; e < 6; ++e) if (s[e] > s[i0]) i0 = e;
        int i1 = (i0 == 0) ? 1 : 0;
#pragma unroll
        for (int e = 0; e < 6; ++e) if (e != i0 && s[e] > s[i1]) i1 = e;
        float g0 = s[i0] * inv, g1 = s[i1] * inv;
        int a = min(i0, i1), b = max(i0, i1);
        const int PB[5] = {0, 5, 9, 12, 14};
        int p = PB[a] + (b - a - 1);
        pid[i] = p;
        gA[i] = (a == i0) ? g0 : g1;
        gB[i] = (a == i0) ? g1 : g0;
        atomicAdd(&lcnt[p], 1);
    }
    __syncthreads();
    if (tid < 15 && lcnt[tid] > 0) atomicAdd(&counts[tid], lcnt[tid]);
}

// ---------- scan: P-padded bucket offsets + tile->pair map ----------
__global__ void k_scan(const int* __restrict__ counts, int* __restrict__ offs,
                       int* __restrict__ tile_pair, int TMAX, int P) {
    __shared__ int so[16];
    if (threadIdx.x == 0) {
        int acc = 0;
        for (int p = 0; p < 15; ++p) { so[p] = acc; acc += (counts[p] + P - 1) & ~(P - 1); }
        so[15] = acc;
        for (int p = 0; p < 16; ++p) offs[p] = so[p];
    }
    __syncthreads();
    for (int t = threadIdx.x; t < TMAX; t += blockDim.x) {
        int tP = t * P;
        if (tP < so[15]) {
            int p = 0;
            while (!(tP >= so[p] && tP < so[p + 1])) ++p;
            tile_pair[t] = p;
        }
    }
}

// ---------- scatter atoms into pair buckets ----------
__global__ void k_scatter(const int* __restrict__ pid, const float* __restrict__ gA,
                          const float* __restrict__ gB, const int* __restrict__ offs,
                          int* __restrict__ cursors, int* __restrict__ idxl,
                          float* __restrict__ gAl, float* __restrict__ gBl, int N) {
    __shared__ int lcnt[16], lbase[16];
    int tid = threadIdx.x;
    if (tid < 16) lcnt[tid] = 0;
    __syncthreads();
    int i = blockIdx.x * 256 + tid;
    int p = -1, rank = 0;
    if (i < N) { p = pid[i]; rank = atomicAdd(&lcnt[p], 1); }
    __syncthreads();
    if (tid < 15 && lcnt[tid] > 0) lbase[tid] = atomicAdd(&cursors[tid], lcnt[tid]);
    __syncthreads();
    if (i < N) {
        int slot = offs[p] + lbase[p] + rank;
        idxl[slot] = i; gAl[slot] = gA[i]; gBl[slot] = gB[i];
    }
}

// ---------- gather X rows into bucket-slot order, fp32 -> bf16 ----------
__global__ void k_gather(const float* __restrict__ X, const int* __restrict__ idxl,
                         unsigned short* __restrict__ Xbf, int CAP) {
    int i = blockIdx.x * 256 + threadIdx.x;     // unit = 8 elements
    int slot = i >> 6;
    if (slot >= CAP) return;
    int k8 = (i & 63) * 8;
    int gi = idxl[slot];
    ushort4 pk0 = {0, 0, 0, 0}, pk1 = {0, 0, 0, 0};
    if (gi >= 0) {
        f32x4 v0 = __builtin_nontemporal_load(
            reinterpret_cast<const f32x4*>(X + (size_t)gi * IN_F + k8));
        f32x4 v1 = __builtin_nontemporal_load(
            reinterpret_cast<const f32x4*>(X + (size_t)gi * IN_F + k8 + 4));
        pk0.x = f2bf(v0.x); pk0.y = f2bf(v0.y); pk0.z = f2bf(v0.z); pk0.w = f2bf(v0.w);
        pk1.x = f2bf(v1.x); pk1.y = f2bf(v1.y); pk1.z = f2bf(v1.z); pk1.w = f2bf(v1.w);
    }
    *reinterpret_cast<ushort4*>(Xbf + (size_t)slot * 512 + k8) = pk0;
    *reinterpret_cast<ushort4*>(Xbf + (size_t)slot * 512 + k8 + 4) = pk1;
}

// =================== v2: TILE=128, W+X streamed, wave tile 64x64 ===================
__global__ __launch_bounds__(512, 2) void k_moe_v2(
    const unsigned short* __restrict__ Xbf,     // [CAP][512] bf16 (slot order)
    const unsigned short* __restrict__ W1b,     // [8][512][512] bf16 plain
    const unsigned short* __restrict__ W2b,     // [8][256][512] bf16 plain
    const int* __restrict__ idxl, const float* __restrict__ gAl,
    const float* __restrict__ gBl, const int* __restrict__ tile_pair,
    const float* __restrict__ rb1, const float* __restrict__ rb2,
    const float* __restrict__ sb1, const float* __restrict__ sb2,
    float* __restrict__ Y)
{
    int t;
    {
        const int nwg = (int)gridDim.x;
        const int q = nwg >> 3, r = nwg & 7;
        const int xcd = (int)blockIdx.x & 7;
        const int idx = (int)blockIdx.x >> 3;
        t = (xcd < r ? xcd * (q + 1) : r * (q + 1) + (xcd - r) * q) + idx;
    }
    const int p = tile_pair[t];
    if (p < 0) return;
    int ea = 0, eb = 1;
    {
        int pp = p;
#pragma unroll
        for (int a = 0; a < 5; ++a) {
            int span = 5 - a;
            if (pp < span) { ea = a; eb = a + 1 + pp; break; }
            pp -= span;
        }
    }

    __shared__ __align__(16) unsigned short Wl[3][8192];   // 48 KB (chunks [256][32])
    __shared__ __align__(16) unsigned short Xl[3][4096];   // 24 KB (chunks [128][32])
    __shared__ __align__(16) unsigned short hsl[32768];    // 64 KB ([128][256] swz)
    __shared__ float gsA[128], gsB[128];
    __shared__ int idxs[128];

    const int tid  = threadIdx.x;
    const int w    = tid >> 6;
    const int lane = tid & 63;
    const int quad = lane >> 4;
    const int l16  = lane & 15;
    const int mw   = w >> 2;          // atom half (0..1): rows mw*64..mw*64+63
    const int nw   = w & 3;           // 64-col group

    // per-lane DMA source offsets (inverse swizzle baked into global addr;
    // LDS dest stays linear: lane writes bytes base + lane*16).
    const int kxs = (((lane & 3) ^ ((lane >> 3) & 3)) << 3);          // col elems
    const size_t wg = (size_t)(32 * w + (lane >> 2)) * 512 + kxs;     // W chunks
    const size_t xg = ((size_t)t * 128 + 16 * w + (lane >> 2)) * 512 + kxs;

    // ds_read offsets (swizzled): slot' = quad ^ ((row>>1)&3), row%2 bits in l16
    const int wswz = ((quad ^ ((l16 >> 1) & 3)) << 3);
    const int wro  = (nw * 64 + l16) * 32 + wswz;     // + nt*512 (16 rows)
    const int xro  = (mw * 64 + l16) * 32 + wswz;     // + mt*512
    const int hro  = (mw * 64 + l16) * 256;           // + mt*4096; + slot'*8

    unsigned short* const wdst = &Wl[0][0];   // slot s: +s*8192; wave: +w*1024
    unsigned short* const xdst = &Xl[0][0];   // slot s: +s*4096; wave: +w*512

    // stage helpers: A = W1 chunk kq (2 ops) + X chunk kq (1 op); B = W2 (2 ops)
    auto stageA = [&](int s, const unsigned short* w1u, int kq) {
        dma16(w1u + wg + kq * 32,        wdst + s * 8192 + w * 1024);
        dma16(w1u + wg + 8192 + kq * 32, wdst + s * 8192 + w * 1024 + 512);
        dma16(Xbf + xg + kq * 32,        xdst + s * 4096 + w * 512);
    };
    auto stageB = [&](int s, const unsigned short* w2u, int b) {
        dma16(w2u + wg + b * 32,        wdst + s * 8192 + w * 1024);
        dma16(w2u + wg + 8192 + b * 32, wdst + s * 8192 + w * 1024 + 512);
    };

    // pass 0 uniform bases (ex = ea, j = 0)
    const unsigned short* w1u0 = W1b + (size_t)ea * 262144;

    // prologue: stream chunks 0,1 of pass 0 (6 vm ops)
    stageA(0, w1u0, 0);
    stageA(1, w1u0, 1);

    if (tid < 128) {
        int slot = t * 128 + tid;
        int gi = idxl[slot];
        idxs[tid] = gi;
        gsA[tid] = (gi >= 0) ? gAl[slot] : 0.f;
        gsB[tid] = (gi >= 0) ? gBl[slot] : 0.f;
    }
    WAIT_LGKM0;
    __builtin_amdgcn_s_barrier();     // idxs/gs published (DMA still in flight)

    f32x4 outacc[4][4] = {};          // 64 atoms x 64 out cols per wave
    float gr[16];

    for (int p8 = 0; p8 < 8; ++p8) {
        const int ei = p8 >> 1, j = p8 & 1;
        const int ex = (ei == 0) ? ea : (ei == 1) ? eb : (ei + 4);
        const unsigned short* w1u = W1b + (size_t)ex * 262144 + (size_t)j * 131072;
        const unsigned short* w2u = W2b + (size_t)ex * 131072 + (size_t)j * 256;
        const float* b1 = (ex < 6) ? rb1 + ex * HID   : sb1 + (ex - 6) * HID;
        const float* b2 = (ex < 6) ? rb2 + ex * OUT_F : sb2 + (ex - 6) * OUT_F;
        // next pass bases (for cross-pass prefetch at b=6,7)
        const int p8n = p8 + 1;
        const int ein = p8n >> 1, jn = p8n & 1;
        const int exn = (ein == 0) ? ea : (ein == 1) ? eb : (ein + 4);
        const unsigned short* w1un = (p8 < 7)
            ? W1b + (size_t)exn * 262144 + (size_t)jn * 131072 : w1u;

        if (j == 0) {
#pragma unroll
            for (int mt = 0; mt < 4; ++mt)
#pragma unroll
                for (int r = 0; r < 4; ++r) {
                    int row = mw * 64 + mt * 16 + quad * 4 + r;
                    gr[mt * 4 + r] = (ei == 0) ? gsA[row] : (ei == 1) ? gsB[row] : 1.f;
                }
        }

        f32x4 acc[4][4] = {};

        // ---- phase A: chunks 0..15 (W1 + X), acc += X @ W1^T
#pragma unroll
        for (int c = 0; c < 16; ++c) {
            WAIT_LGKM0;
            if (c < 15) { WAIT_VM3; } else { WAIT_VM2; }
            __builtin_amdgcn_s_barrier();
            if (c <= 13)      stageA((c + 2) % 3, w1u, c + 2);
            else if (c == 14) stageB(1, w2u, 0);            // 16%3
            else              stageB(2, w2u, 1);            // 17%3
            const unsigned short* wc = &Wl[c % 3][0];
            const unsigned short* xc = &Xl[c % 3][0];
            short8 bfr[4], afr[4];
#pragma unroll
            for (int nt = 0; nt < 4; ++nt)
                bfr[nt] = *reinterpret_cast<const short8*>(wc + wro + nt * 512);
#pragma unroll
            for (int mt = 0; mt < 4; ++mt)
                afr[mt] = *reinterpret_cast<const short8*>(xc + xro + mt * 512);
            __builtin_amdgcn_s_setprio(1);
#pragma unroll
            for (int mt = 0; mt < 4; ++mt)
#pragma unroll
                for (int nt = 0; nt < 4; ++nt)
                    acc[mt][nt] = __builtin_amdgcn_mfma_f32_16x16x32_bf16(
                        afr[mt], bfr[nt], acc[mt][nt], 0, 0, 0);
            __builtin_amdgcn_s_setprio(0);
        }

        // silu + gate -> hs (swizzled writes; published at next iter's barrier)
#pragma unroll
        for (int mt = 0; mt < 4; ++mt)
#pragma unroll
            for (int nt = 0; nt < 4; ++nt) {
                int col = nw * 64 + nt * 16 + l16;
                float bb = b1[j * 256 + col];
#pragma unroll
                for (int r = 0; r < 4; ++r) {
                    int row = mw * 64 + mt * 16 + quad * 4 + r;
                    float v = acc[mt][nt][r] + bb;
                    float h = v / (1.f + __expf(-v));
                    int sl = ((col >> 3) ^ (row & 7));
                    hsl[row * 256 + sl * 8 + (col & 7)] = f2bf(h * gr[mt * 4 + r]);
                }
            }

        // ---- phase B: chunks 16..23 (W2), outacc += H' @ W2^T
#pragma unroll
        for (int b = 0; b < 8; ++b) {
            WAIT_LGKM0;                        // incl. my hs ds_writes
            if (b < 7) { WAIT_VM2; }
            else if (p8 < 7) { WAIT_VM3; } else { WAIT_VM0; }
            __builtin_amdgcn_s_barrier();
            if (b <= 5)               stageB(b % 3, w2u, b + 2);   // (18+b)%3
            else if (b == 6 && p8 < 7) stageA(0, w1un, 0);         // 24%3
            else if (b == 7 && p8 < 7) stageA(1, w1un, 1);         // 25%3
            const unsigned short* wc = &Wl[(b + 1) % 3][0];        // (16+b)%3
            short8 bfr[4], afr[4];
#pragma unroll
            for (int nt = 0; nt < 4; ++nt)
                bfr[nt] = *reinterpret_cast<const short8*>(wc + wro + nt * 512);
#pragma unroll
            for (int mt = 0; mt < 4; ++mt)
                afr[mt] = *reinterpret_cast<const short8*>(
                    hsl + hro + mt * 4096 + ((((b * 4) + quad) ^ (l16 & 7)) << 3));
            __builtin_amdgcn_s_setprio(1);
#pragma unroll
            for (int mt = 0; mt < 4; ++mt)
#pragma unroll
                for (int nt = 0; nt < 4; ++nt)
                    outacc[mt][nt] = __builtin_amdgcn_mfma_f32_16x16x32_bf16(
                        afr[mt], bfr[nt], outacc[mt][nt], 0, 0, 0);
            __builtin_amdgcn_s_setprio(0);
        }

        // ---- + gate * b2 once per expert (end of j==1)
        if (j == 1) {
#pragma unroll
            for (int mt = 0; mt < 4; ++mt)
#pragma unroll
                for (int nt = 0; nt < 4; ++nt) {
                    float bb = b2[nw * 64 + nt * 16 + l16];
#pragma unroll
                    for (int r = 0; r < 4; ++r)
                        outacc[mt][nt][r] += gr[mt * 4 + r] * bb;
                }
        }
    }

    // write Y nontemporal
#pragma unroll
    for (int mt = 0; mt < 4; ++mt)
#pragma unroll
        for (int nt = 0; nt < 4; ++nt)
#pragma unroll
            for (int r = 0; r < 4; ++r) {
                int row = mw * 64 + mt * 16 + quad * 4 + r;
                int gi = idxs[row];
                if (gi >= 0)
                    __builtin_nontemporal_store(outacc[mt][nt][r],
                        Y + (size_t)gi * OUT_F + nw * 64 + nt * 16 + l16);
            }
}

// =================== v1 fallback: round-8 kernel verbatim (TILE=64) ===================
#define TILE 64
#define CH   8192

__device__ __forceinline__ void stage_chunk(const unsigned short* g,
                                            unsigned short* l, int w, int lane) {
    dma16(g + w * 1024 +       lane * 8, l + w * 1024);
    dma16(g + w * 1024 + 512 + lane * 8, l + w * 1024 + 512);
}

__global__ __launch_bounds__(512, 2) void k_moe_v1(
    const float* __restrict__ X,
    const unsigned short* __restrict__ W1pk,
    const unsigned short* __restrict__ W2pk,
    const int* __restrict__ idxl, const float* __restrict__ gAl,
    const float* __restrict__ gBl, const int* __restrict__ tile_pair,
    const float* __restrict__ rb1, const float* __restrict__ rb2,
    const float* __restrict__ sb1, const float* __restrict__ sb2,
    float* __restrict__ Y)
{
    int t;
    {
        const int nwg = (int)gridDim.x;
        const int q = nwg >> 3, r = nwg & 7;
        const int xcd = (int)blockIdx.x & 7;
        const int idx = (int)blockIdx.x >> 3;
        t = (xcd < r ? xcd * (q + 1) : r * (q + 1) + (xcd - r) * q) + idx;
    }
    const int p = tile_pair[t];
    if (p < 0) return;
    int ea = 0, eb = 1;
    {
        int pp = p;
#pragma unroll
        for (int a = 0; a < 5; ++a) {
            int span = 5 - a;
            if (pp < span) { ea = a; eb = a + 1 + pp; break; }
            pp -= span;
        }
    }

    __shared__ __align__(16) unsigned short xs[TILE][520];
    __shared__ __align__(16) unsigned short hs[TILE][264];
    __shared__ __align__(16) unsigned short wlds[3][CH];
    __shared__ float gsA[TILE], gsB[TILE];
    __shared__ int idxs[TILE];

    const int tid = threadIdx.x;
    if (tid < TILE) {
        int slot = t * TILE + tid;
        int gi = idxl[slot];
        idxs[tid] = gi;
        gsA[tid] = (gi >= 0) ? gAl[slot] : 0.f;
        gsB[tid] = (gi >= 0) ? gBl[slot] : 0.f;
    }
    __syncthreads();

    for (int i = tid; i < TILE * 128; i += 512) {
        int r = i >> 7, c4 = i & 127;
        int gi = idxs[r]; if (gi < 0) gi = 0;
        f32x4 v = __builtin_nontemporal_load(
            reinterpret_cast<const f32x4*>(X + (size_t)gi * IN_F) + c4);
        ushort4 pk;
        pk.x = f2bf(v.x); pk.y = f2bf(v.y); pk.z = f2bf(v.z); pk.w = f2bf(v.w);
        *reinterpret_cast<ushort4*>(&xs[r][c4 * 4]) = pk;
    }
    WAIT_VM0;

    const int w    = tid >> 6;
    const int lane = tid & 63;
    const int mw   = w >> 2;
    const int nw   = w & 3;
    const int quad = lane >> 4;
    const int l16  = lane & 15;
    const int swz  = ((quad ^ ((l16 >> 1) & 3)) << 3);
    const int wrow = (nw * 64 + l16) * 32;

    f32x4 outacc[2][4] = {};

    for (int ei = 0; ei < 4; ++ei) {
        const int ex = (ei == 0) ? ea : (ei == 1) ? eb : (ei + 4);
        const float* b1 = (ex < 6) ? rb1 + ex * HID   : sb1 + (ex - 6) * HID;
        const float* b2 = (ex < 6) ? rb2 + ex * OUT_F : sb2 + (ex - 6) * OUT_F;

        float gr[8];
#pragma unroll
        for (int mt = 0; mt < 2; ++mt)
#pragma unroll
            for (int r = 0; r < 4; ++r) {
                int row = mw * 32 + mt * 16 + quad * 4 + r;
                gr[mt * 4 + r] = (ei == 0) ? gsA[row] : (ei == 1) ? gsB[row] : 1.f;
            }

        for (int j = 0; j < 2; ++j) {
            const unsigned short* w1c = W1pk + ((size_t)ex * 2 + j) * (16 * CH);
            const unsigned short* w2c = W2pk + ((size_t)ex * 2 + j) * (8 * CH);

            stage_chunk(w1c,      wlds[0], w, lane);
            stage_chunk(w1c + CH, wlds[1], w, lane);

            f32x4 acc[2][4] = {};

#pragma unroll
            for (int c = 0; c < 16; ++c) {
                WAIT_LGKM0;
                WAIT_VM2;
                __builtin_amdgcn_s_barrier();
                if (c + 2 < 16)
                    stage_chunk(w1c + (c + 2) * CH, wlds[(c + 2) % 3], w, lane);
                else
                    stage_chunk(w2c + (c + 2 - 16) * CH, wlds[(c + 2) % 3], w, lane);
                const unsigned short* cur = wlds[c % 3];
                short8 b[4], a[2];
#pragma unroll
                for (int nt = 0; nt < 4; ++nt)
                    b[nt] = *reinterpret_cast<const short8*>(cur + wrow + nt * 512 + swz);
#pragma unroll
                for (int mt = 0; mt < 2; ++mt)
                    a[mt] = *reinterpret_cast<const short8*>(
                        &xs[mw * 32 + mt * 16 + l16][c * 32 + quad * 8]);
#pragma unroll
                for (int mt = 0; mt < 2; ++mt)
#pragma unroll
                    for (int nt = 0; nt < 4; ++nt)
                        acc[mt][nt] = __builtin_amdgcn_mfma_f32_16x16x32_bf16(
                            a[mt], b[nt], acc[mt][nt], 0, 0, 0);
            }

#pragma unroll
            for (int mt = 0; mt < 2; ++mt)
#pragma unroll
                for (int nt = 0; nt < 4; ++nt) {
                    int hcol = nw * 64 + nt * 16 + l16;
                    float bb = b1[j * 256 + hcol];
#pragma unroll
                    for (int r = 0; r < 4; ++r) {
                        int row = mw * 32 + mt * 16 + quad * 4 + r;
                        float v = acc[mt][nt][r] + bb;
                        float h = v / (1.f + __expf(-v));
                        hs[row][hcol] = f2bf(h * gr[mt * 4 + r]);
                    }
                }

#pragma unroll
            for (int c = 16; c < 24; ++c) {
                WAIT_LGKM0;
                if (c < 23) { WAIT_VM2; } else { WAIT_VM0; }
                __builtin_amdgcn_s_barrier();
                if (c + 2 < 24)
                    stage_chunk(w2c + (c + 2 - 16) * CH, wlds[(c + 2) % 3], w, lane);
                const unsigned short* cur = wlds[c % 3];
                short8 b[4], a[2];
#pragma unroll
                for (int nt = 0; nt < 4; ++nt)
                    b[nt] = *reinterpret_cast<const short8*>(cur + wrow + nt * 512 + swz);
#pragma unroll
                for (int mt = 0; mt < 2; ++mt)
                    a[mt] = *reinterpret_cast<const short8*>(
                        &hs[mw * 32 + mt * 16 + l16][(c - 16) * 32 + quad * 8]);
#pragma unroll
                for (int mt = 0; mt < 2; ++mt)
#pragma unroll
                    for (int nt = 0; nt < 4; ++nt)
                        outacc[mt][nt] = __builtin_amdgcn_mfma_f32_16x16x32_bf16(
                            a[mt], b[nt], outacc[mt][nt], 0, 0, 0);
            }
        }

#pragma unroll
        for (int mt = 0; mt < 2; ++mt)
#pragma unroll
            for (int nt = 0; nt < 4; ++nt) {
                float bb = b2[nw * 64 + nt * 16 + l16];
#pragma unroll
                for (int r = 0; r < 4; ++r)
                    outacc[mt][nt][r] += gr[mt * 4 + r] * bb;
            }
    }

#pragma unroll
    for (int mt = 0; mt < 2; ++mt)
#pragma unroll
        for (int nt = 0; nt < 4; ++nt)
#pragma unroll
            for (int r = 0; r < 4; ++r) {
                int row = mw * 32 + mt * 16 + quad * 4 + r;
                int gi = idxs[row];
                if (gi >= 0)
                    __builtin_nontemporal_store(outacc[mt][nt][r],
                        Y + (size_t)gi * OUT_F + nw * 64 + nt * 16 + l16);
            }
}

extern "C" void kernel_launch(void* const* d_in, const int* in_sizes, int n_in,
                              void* d_out, int out_size, void* d_ws, size_t ws_size,
                              hipStream_t stream) {
    const float* X       = (const float*)d_in[0];
    const int*   species = (const int*)d_in[1];
    const float* emb     = (const float*)d_in[2];
    const float* Wr      = (const float*)d_in[3];
    const float* rW1     = (const float*)d_in[4];
    const float* rb1     = (const float*)d_in[5];
    const float* rW2     = (const float*)d_in[6];
    const float* rb2     = (const float*)d_in[7];
    const float* sW1     = (const float*)d_in[8];
    const float* sb1     = (const float*)d_in[9];
    const float* sW2     = (const float*)d_in[10];
    const float* sb2     = (const float*)d_in[11];
    float* Y = (float*)d_out;
    const int N = in_sizes[1];

    // ---- decide v2 (TILE=128 + Xbf) vs v1 fallback (TILE=64) by ws budget
    const int TMAX128 = (N + 15 * 128 + 127) / 128;
    const int CAP128  = TMAX128 * 128;
    const int TMAX64  = (N + 15 * 64 + 63) / 64;
    const int CAP64   = TMAX64 * 64;

    size_t fixed = 0;
    auto sz = [&](size_t b) { fixed += (b + 255) & ~(size_t)255; };
    sz((size_t)8 * HID * IN_F * 2); sz((size_t)8 * OUT_F * HID * 2);
    sz((size_t)N * 4); sz((size_t)N * 4); sz((size_t)N * 4);
    sz(64); sz(64); sz(64);
    sz((size_t)CAP128 * 4); sz((size_t)CAP128 * 4); sz((size_t)CAP128 * 4);
    sz((size_t)TMAX128 * 4);
    const size_t xbf_bytes = (size_t)CAP128 * 512 * 2;
    const bool big = (fixed + xbf_bytes + 256) <= ws_size;

    const int P    = big ? 128 : 64;
    const int TMAX = big ? TMAX128 : TMAX64;
    const int CAP  = big ? CAP128 : CAP64;

    size_t o = 0;
    auto take = [&](size_t bytes) { size_t r = o; o += (bytes + 255) & ~(size_t)255; return r; };
    char* ws = (char*)d_ws;
    unsigned short* w1bf = (unsigned short*)(ws + take((size_t)8 * HID * IN_F * 2));
    unsigned short* w2bf = (unsigned short*)(ws + take((size_t)8 * OUT_F * HID * 2));
    int*   pid      = (int*)  (ws + take((size_t)N * 4));
    float* gA       = (float*)(ws + take((size_t)N * 4));
    float* gB       = (float*)(ws + take((size_t)N * 4));
    int*   counts   = (int*)  (ws + take(64));
    int*   cursors  = (int*)  (ws + take(64));
    int*   offs     = (int*)  (ws + take(64));
    int*   idxl     = (int*)  (ws + take((size_t)CAP * 4));
    float* gAl      = (float*)(ws + take((size_t)CAP * 4));
    float* gBl      = (float*)(ws + take((size_t)CAP * 4));
    int*   tile_pair= (int*)  (ws + take((size_t)TMAX * 4));
    unsigned short* Xbf = big ? (unsigned short*)(ws + take(xbf_bytes)) : nullptr;

    k_prep<<<12288, 256, 0, stream>>>(rW1, sW1, rW2, sW2, w1bf, w2bf,
                                      counts, cursors, idxl, tile_pair,
                                      CAP, TMAX, big ? 0 : 1);
    k_router<<<(N + 255) / 256, 256, 0, stream>>>(species, emb, Wr, pid, gA, gB, counts, N);
    k_scan<<<1, 256, 0, stream>>>(counts, offs, tile_pair, TMAX, P);
    k_scatter<<<(N + 255) / 256, 256, 0, stream>>>(pid, gA, gB, offs, cursors, idxl, gAl, gBl, N);
    if (big) {
        k_gather<<<CAP / 4, 256, 0, stream>>>(X, idxl, Xbf, CAP);
        k_moe_v2<<<TMAX, 512, 0, stream>>>(Xbf, w1bf, w2bf, idxl, gAl, gBl, tile_pair,
                                           rb1, rb2, sb1, sb2, Y);
    } else {
        k_moe_v1<<<TMAX, 512, 0, stream>>>(X, w1bf, w2bf, idxl, gAl, gBl, tile_pair,
                                           rb1, rb2, sb1, sb2, Y);
    }
}

// Round 6
// 870.035 us; speedup vs baseline: 1.3467x; 1.3467x over previous
//
#include <hip/hip_runtime.h>
#include <hip/hip_bf16.h>

// MoEReadout round 10: back to v1 dataflow (X LDS-resident, W streamed),
// with K=64 double-iterations to halve barrier/wait overhead.
//  - W ring of 4x16KB chunks; per double-iter: {12 ds_read_b128, 16 MFMA,
//    lgkm0, vmcnt(0) [drains loads issued a full iter earlier ~ free],
//    barrier, stage 2 chunks}. Cross-pass 28-chunk stream (24 + next 0..3).
//  - xs/hs stored as chunked [kq][64][32] XOR-swizzled (16B slot ^=
//    (row>>1)&3), matching the packed-W swizzle -> conflict-free b128.
//  - gates + atom indices read directly from global (L2-hot) -> LDS freed;
//    total LDS = 64KB(xs) + 32KB(hs) + 64KB(Wring) = 163840 B exactly.
//  - setprio(1) around MFMA clusters; XCD-chunked bijective block swizzle.

typedef __attribute__((ext_vector_type(8))) short short8;   // 8 x bf16
typedef __attribute__((ext_vector_type(4))) float f32x4;    // MFMA acc / 16B load

#define IN_F 512
#define HID  512
#define OUT_F 256
#define TILE 64
#define CH   8192   // shorts per 16KB chunk (256 rows x 32 cols)

#define WAIT_LGKM0 asm volatile("s_waitcnt lgkmcnt(0)" ::: "memory")
#define WAIT_VM4   asm volatile("s_waitcnt vmcnt(4)"   ::: "memory")
#define WAIT_VM0   asm volatile("s_waitcnt vmcnt(0)"   ::: "memory")

__device__ inline unsigned short f2bf(float f) {
    __hip_bfloat16 h = __float2bfloat16(f);
    return *reinterpret_cast<unsigned short*>(&h);
}

__device__ __forceinline__ void dma16(const unsigned short* g, unsigned short* l) {
    __builtin_amdgcn_global_load_lds(
        (const __attribute__((address_space(1))) unsigned int*)(unsigned long long)(const void*)g,
        (__attribute__((address_space(3))) unsigned int*)(unsigned int)(unsigned long long)(void*)l,
        16, 0, 0);
}

// ---------- prep: weight cvt to packed+swizzled chunks + state init ----------
// W1 packed: [ex(8)][j(2)][kq(16)][row(256)][32 cols]; in-row 16B slot s
// stored at s ^ ((row>>1)&3). W2: [ex(8)][j(2)][kq(8)][row(256)][32 cols].
__global__ void k_prep(const float* __restrict__ rW1, const float* __restrict__ sW1,
                       const float* __restrict__ rW2, const float* __restrict__ sW2,
                       unsigned short* __restrict__ w1bf, unsigned short* __restrict__ w2bf,
                       int* __restrict__ counts, int* __restrict__ cursors,
                       int* __restrict__ idxl, int* __restrict__ tile_pair,
                       int CAP, int TMAX) {
    int i = blockIdx.x * 256 + threadIdx.x;
    if (i < 8 * 512 * 512) {
        int low3 = i & 7, sw = (i >> 3) & 3, row = (i >> 5) & 255;
        int kq = (i >> 13) & 15, j = (i >> 17) & 1, ex = i >> 18;
        int col = ((sw ^ ((row >> 1) & 3)) << 3) + low3;
        int hrow = j * 256 + row, kcol = kq * 32 + col;
        float v = (ex < 6) ? rW1[((size_t)ex * 512 + hrow) * 512 + kcol]
                           : sW1[((size_t)(ex - 6) * 512 + hrow) * 512 + kcol];
        w1bf[i] = f2bf(v);
    }
    if (i < 8 * 256 * 512) {
        int low3 = i & 7, sw = (i >> 3) & 3, row = (i >> 5) & 255;
        int kq = (i >> 13) & 7, j = (i >> 16) & 1, ex = i >> 17;
        int col = ((sw ^ ((row >> 1) & 3)) << 3) + low3;
        int kcol = j * 256 + kq * 32 + col;
        float v = (ex < 6) ? rW2[((size_t)ex * 256 + row) * 512 + kcol]
                           : sW2[((size_t)(ex - 6) * 256 + row) * 512 + kcol];
        w2bf[i] = f2bf(v);
    }
    if (i < 16) { counts[i] = 0; cursors[i] = 0; }
    if (i < TMAX) tile_pair[i] = -1;
    if (i < CAP) idxl[i] = -1;
}

// ---------- router: top-2 -> pair id + gates ----------
__global__ void k_router(const int* __restrict__ species, const float* __restrict__ emb,
                         const float* __restrict__ Wr,
                         int* __restrict__ pid, float* __restrict__ gA, float* __restrict__ gB,
                         int* __restrict__ counts, int N) {
    __shared__ int lcnt[16];
    int tid = threadIdx.x;
    if (tid < 16) lcnt[tid] = 0;
    __syncthreads();
    int i = blockIdx.x * 256 + tid;
    if (i < N) {
        int z = species[i];
        float u[16];
#pragma unroll
        for (int k = 0; k < 16; ++k) {
            float v = emb[z * 16 + k];
            u[k] = v / (1.f + __expf(-v));
        }
        float s[6];
        float mx = -1e30f;
#pragma unroll
        for (int e = 0; e < 6; ++e) {
            float a = 0.f;
#pragma unroll
            for (int k = 0; k < 16; ++k) a += u[k] * Wr[e * 16 + k];
            s[e] = a;
            mx = fmaxf(mx, a);
        }
        float sum = 0.f;
#pragma unroll
        for (int e = 0; e < 6; ++e) { s[e] = __expf(s[e] - mx); sum += s[e]; }
        float inv = 1.f / sum;
        int i0 = 0;
#pragma unroll
        for (int e = 1; e < 6; ++e) if (s[e] > s[i0]) i0 = e;
        int i1 = (i0 == 0) ? 1 : 0;
#pragma unroll
        for (int e = 0; e < 6; ++e) if (e != i0 && s[e] > s[i1]) i1 = e;
        float g0 = s[i0] * inv, g1 = s[i1] * inv;
        int a = min(i0, i1), b = max(i0, i1);
        const int PB[5] = {0, 5, 9, 12, 14};
        int p = PB[a] + (b - a - 1);
        pid[i] = p;
        gA[i] = (a == i0) ? g0 : g1;
        gB[i] = (a == i0) ? g1 : g0;
        atomicAdd(&lcnt[p], 1);
    }
    __syncthreads();
    if (tid < 15 && lcnt[tid] > 0) atomicAdd(&counts[tid], lcnt[tid]);
}

// ---------- scan: 64-padded bucket offsets + tile->pair map ----------
__global__ void k_scan(const int* __restrict__ counts, int* __restrict__ offs,
                       int* __restrict__ tile_pair, int TMAX) {
    __shared__ int so[16];
    if (threadIdx.x == 0) {
        int acc = 0;
        for (int p = 0; p < 15; ++p) { so[p] = acc; acc += (counts[p] + 63) & ~63; }
        so[15] = acc;
        for (int p = 0; p < 16; ++p) offs[p] = so[p];
    }
    __syncthreads();
    for (int t = threadIdx.x; t < TMAX; t += blockDim.x) {
        int t64 = t * 64;
        if (t64 < so[15]) {
            int p = 0;
            while (!(t64 >= so[p] && t64 < so[p + 1])) ++p;
            tile_pair[t] = p;
        }
    }
}

// ---------- scatter atoms into pair buckets ----------
__global__ void k_scatter(const int* __restrict__ pid, const float* __restrict__ gA,
                          const float* __restrict__ gB, const int* __restrict__ offs,
                          int* __restrict__ cursors, int* __restrict__ idxl,
                          float* __restrict__ gAl, float* __restrict__ gBl, int N) {
    __shared__ int lcnt[16], lbase[16];
    int tid = threadIdx.x;
    if (tid < 16) lcnt[tid] = 0;
    __syncthreads();
    int i = blockIdx.x * 256 + tid;
    int p = -1, rank = 0;
    if (i < N) { p = pid[i]; rank = atomicAdd(&lcnt[p], 1); }
    __syncthreads();
    if (tid < 15 && lcnt[tid] > 0) lbase[tid] = atomicAdd(&cursors[tid], lcnt[tid]);
    __syncthreads();
    if (i < N) {
        int slot = offs[p] + lbase[p] + rank;
        idxl[slot] = i; gAl[slot] = gA[i]; gBl[slot] = gB[i];
    }
}

// ---------- fused MoE MLP over pair-homogeneous 64-atom tiles ----------
// 512 threads = 8 waves (mw = w>>2 atom half, nw = w&3 64-col group).
// LDS = 163840 B exactly. K=64 double-iters over the 24-chunk stream
// (+4 next-pass chunks), ring-4 W buffer.
__global__ __launch_bounds__(512, 2) void k_moe(
    const float* __restrict__ X,
    const unsigned short* __restrict__ W1pk,
    const unsigned short* __restrict__ W2pk,
    const int* __restrict__ idxl, const float* __restrict__ gAl,
    const float* __restrict__ gBl, const int* __restrict__ tile_pair,
    const float* __restrict__ rb1, const float* __restrict__ rb2,
    const float* __restrict__ sb1, const float* __restrict__ sb2,
    float* __restrict__ Y)
{
    // Bijective XCD-chunked swizzle (m204): per-XCD working set ~1 pair.
    int t;
    {
        const int nwg = (int)gridDim.x;
        const int q = nwg >> 3, r = nwg & 7;
        const int xcd = (int)blockIdx.x & 7;
        const int idx = (int)blockIdx.x >> 3;
        t = (xcd < r ? xcd * (q + 1) : r * (q + 1) + (xcd - r) * q) + idx;
    }
    const int p = tile_pair[t];
    if (p < 0) return;
    int ea = 0, eb = 1;
    {
        int pp = p;
#pragma unroll
        for (int a = 0; a < 5; ++a) {
            int span = 5 - a;
            if (pp < span) { ea = a; eb = a + 1 + pp; break; }
            pp -= span;
        }
    }

    __shared__ __align__(16) unsigned short xs[16][64][32];   // 64 KB
    __shared__ __align__(16) unsigned short hl[8][64][32];    // 32 KB
    __shared__ __align__(16) unsigned short wl[4][CH];        // 64 KB

    const int tid  = threadIdx.x;
    const int w    = tid >> 6;
    const int lane = tid & 63;
    const int quad = lane >> 4;
    const int l16  = lane & 15;
    const int mw   = w >> 2;          // atom half (0..1)
    const int nw   = w & 3;           // 64-col group (0..3)

    // ---- stage X tile (fp32 -> bf16) into chunked+swizzled xs
    for (int i = tid; i < TILE * 128; i += 512) {
        int row = i >> 7, c4 = i & 127;         // c4: f32x4 index 0..127
        int gi = idxl[t * TILE + row]; if (gi < 0) gi = 0;
        f32x4 v = __builtin_nontemporal_load(
            reinterpret_cast<const f32x4*>(X + (size_t)gi * IN_F) + c4);
        ushort4 pk;
        pk.x = f2bf(v.x); pk.y = f2bf(v.y); pk.z = f2bf(v.z); pk.w = f2bf(v.w);
        int kq   = c4 >> 3;                               // K chunk
        int slot = ((c4 >> 1) & 3) ^ ((row >> 1) & 3);    // swizzled 16B slot
        *reinterpret_cast<ushort4*>(&xs[kq][row][slot * 8 + (c4 & 1) * 4]) = pk;
    }
    WAIT_VM0;     // all X/idxl loads consumed; vmcnt accounting exact below

    // stage one 16KB W chunk into ring buf (wave-uniform LDS base + lane*16B)
    auto stW = [&](const unsigned short* src, int buf) {
        dma16(src + w * 1024 +       lane * 8, &wl[buf][w * 1024]);
        dma16(src + w * 1024 + 512 + lane * 8, &wl[buf][w * 1024 + 512]);
    };

    const int swz  = ((quad ^ ((l16 >> 1) & 3)) << 3);
    const int wro  = (nw * 64 + l16) * 32 + swz;   // + nt*512
    const int xrow = mw * 32 + l16;                // + mt*16

    // prologue: first pass (ex=ea, j=0) chunks 0..3
    {
        const unsigned short* w1c0 = W1pk + (size_t)(ea * 2) * (16 * CH);
        stW(w1c0,          0); stW(w1c0 + CH,     1);
        stW(w1c0 + 2 * CH, 2); stW(w1c0 + 3 * CH, 3);
    }
    WAIT_LGKM0;       // my xs ds_writes retired
    WAIT_VM4;         // chunks 0,1 landed; 2,3 in flight
    __builtin_amdgcn_s_barrier();

    f32x4 outacc[2][4] = {};
    float gr[8];

    for (int p8 = 0; p8 < 8; ++p8) {
        const int ei = p8 >> 1, j = p8 & 1;
        const int ex = (ei == 0) ? ea : (ei == 1) ? eb : (ei + 4);
        const unsigned short* w1c = W1pk + (size_t)(ex * 2 + j) * (16 * CH);
        const unsigned short* w2c = W2pk + (size_t)(ex * 2 + j) * (8 * CH);
        const float* b1 = (ex < 6) ? rb1 + ex * HID   : sb1 + (ex - 6) * HID;
        const float* b2 = (ex < 6) ? rb2 + ex * OUT_F : sb2 + (ex - 6) * OUT_F;
        // next-pass W1 base for cross-pass prefetch
        const int ein = (p8 + 1) >> 1, jn = (p8 + 1) & 1;
        const int exn = (ein == 0) ? ea : (ein == 1) ? eb : (ein + 4);
        const unsigned short* w1cN = W1pk + (size_t)((p8 < 7 ? exn : ex) * 2 + jn) * (16 * CH);

        if (j == 0) {
            const float* gp = (ei == 0) ? gAl : (ei == 1) ? gBl : nullptr;
#pragma unroll
            for (int mt = 0; mt < 2; ++mt)
#pragma unroll
                for (int r = 0; r < 4; ++r) {
                    int row = mw * 32 + mt * 16 + quad * 4 + r;
                    gr[mt * 4 + r] = gp ? gp[t * TILE + row] : 1.f;
                }
        }

        f32x4 acc[2][4] = {};

        // ---- phase A: 8 double-iters, chunks 2d,2d+1 (W1) + xs chunks
#pragma unroll
        for (int d = 0; d < 8; ++d) {
            short8 bfr[2][4], afr[2][2];
#pragma unroll
            for (int kk = 0; kk < 2; ++kk) {
                const unsigned short* wc = &wl[(2 * d + kk) & 3][0];
#pragma unroll
                for (int nt = 0; nt < 4; ++nt)
                    bfr[kk][nt] = *reinterpret_cast<const short8*>(wc + wro + nt * 512);
#pragma unroll
                for (int mt = 0; mt < 2; ++mt)
                    afr[kk][mt] = *reinterpret_cast<const short8*>(
                        &xs[2 * d + kk][xrow + mt * 16][swz]);
            }
            __builtin_amdgcn_s_setprio(1);
#pragma unroll
            for (int kk = 0; kk < 2; ++kk)
#pragma unroll
                for (int mt = 0; mt < 2; ++mt)
#pragma unroll
                    for (int nt = 0; nt < 4; ++nt)
                        acc[mt][nt] = __builtin_amdgcn_mfma_f32_16x16x32_bf16(
                            afr[kk][mt], bfr[kk][nt], acc[mt][nt], 0, 0, 0);
            __builtin_amdgcn_s_setprio(0);
            WAIT_LGKM0;                    // my reads of bufs (2d),(2d+1) retired
            WAIT_VM0;                      // drains stages issued last iter (~free)
            __builtin_amdgcn_s_barrier();
            const int s0 = 2 * d + 4;
            if (s0 < 16) {
                stW(w1c + (size_t)s0 * CH, s0 & 3);
                stW(w1c + (size_t)(s0 + 1) * CH, (s0 + 1) & 3);
            } else {
                stW(w2c + (size_t)(s0 - 16) * CH, s0 & 3);
                stW(w2c + (size_t)(s0 - 15) * CH, (s0 + 1) & 3);
            }
        }

        // ---- silu + gate -> hl (chunked + swizzled)
#pragma unroll
        for (int mt = 0; mt < 2; ++mt)
#pragma unroll
            for (int nt = 0; nt < 4; ++nt) {
                int hcol = nw * 64 + nt * 16 + l16;
                float bb = b1[j * 256 + hcol];
                int kq = hcol >> 5, ic = hcol & 31;
#pragma unroll
                for (int r = 0; r < 4; ++r) {
                    int row = mw * 32 + mt * 16 + quad * 4 + r;
                    float v = acc[mt][nt][r] + bb;
                    float h = v / (1.f + __expf(-v));
                    int sl = (ic >> 3) ^ ((row >> 1) & 3);
                    hl[kq][row][sl * 8 + (ic & 7)] = f2bf(h * gr[mt * 4 + r]);
                }
            }
        WAIT_LGKM0;
        __builtin_amdgcn_s_barrier();      // hl visible to all waves

        // ---- phase B: 4 double-iters, chunks 16..23 (W2) + hl chunks
#pragma unroll
        for (int d = 0; d < 4; ++d) {
            short8 bfr[2][4], afr[2][2];
#pragma unroll
            for (int kk = 0; kk < 2; ++kk) {
                const unsigned short* wc = &wl[(2 * d + kk) & 3][0];   // (16+2d+kk)&3
#pragma unroll
                for (int nt = 0; nt < 4; ++nt)
                    bfr[kk][nt] = *reinterpret_cast<const short8*>(wc + wro + nt * 512);
#pragma unroll
                for (int mt = 0; mt < 2; ++mt)
                    afr[kk][mt] = *reinterpret_cast<const short8*>(
                        &hl[2 * d + kk][xrow + mt * 16][swz]);
            }
            __builtin_amdgcn_s_setprio(1);
#pragma unroll
            for (int kk = 0; kk < 2; ++kk)
#pragma unroll
                for (int mt = 0; mt < 2; ++mt)
#pragma unroll
                    for (int nt = 0; nt < 4; ++nt)
                        outacc[mt][nt] = __builtin_amdgcn_mfma_f32_16x16x32_bf16(
                            afr[kk][mt], bfr[kk][nt], outacc[mt][nt], 0, 0, 0);
            __builtin_amdgcn_s_setprio(0);
            WAIT_LGKM0;
            WAIT_VM0;
            __builtin_amdgcn_s_barrier();
            const int s0 = 20 + 2 * d;
            if (s0 < 24) {
                stW(w2c + (size_t)(s0 - 16) * CH, s0 & 3);
                stW(w2c + (size_t)(s0 - 15) * CH, (s0 + 1) & 3);
            } else if (p8 < 7) {
                stW(w1cN + (size_t)(s0 - 24) * CH, s0 & 3);
                stW(w1cN + (size_t)(s0 - 23) * CH, (s0 + 1) & 3);
            }
        }

        // ---- + gate * b2 at end of each expert (j==1)
        if (j == 1) {
#pragma unroll
            for (int mt = 0; mt < 2; ++mt)
#pragma unroll
                for (int nt = 0; nt < 4; ++nt) {
                    float bb = b2[nw * 64 + nt * 16 + l16];
#pragma unroll
                    for (int r = 0; r < 4; ++r)
                        outacc[mt][nt][r] += gr[mt * 4 + r] * bb;
                }
        }
    }

    // ---- write Y nontemporal (atom index reloaded from global, L2-hot)
#pragma unroll
    for (int mt = 0; mt < 2; ++mt)
#pragma unroll
        for (int r = 0; r < 4; ++r) {
            int row = mw * 32 + mt * 16 + quad * 4 + r;
            int gi = idxl[t * TILE + row];
            if (gi >= 0) {
#pragma unroll
                for (int nt = 0; nt < 4; ++nt)
                    __builtin_nontemporal_store(outacc[mt][nt][r],
                        Y + (size_t)gi * OUT_F + nw * 64 + nt * 16 + l16);
            }
        }
}

extern "C" void kernel_launch(void* const* d_in, const int* in_sizes, int n_in,
                              void* d_out, int out_size, void* d_ws, size_t ws_size,
                              hipStream_t stream) {
    const float* X       = (const float*)d_in[0];
    const int*   species = (const int*)d_in[1];
    const float* emb     = (const float*)d_in[2];
    const float* Wr      = (const float*)d_in[3];
    const float* rW1     = (const float*)d_in[4];
    const float* rb1     = (const float*)d_in[5];
    const float* rW2     = (const float*)d_in[6];
    const float* rb2     = (const float*)d_in[7];
    const float* sW1     = (const float*)d_in[8];
    const float* sb1     = (const float*)d_in[9];
    const float* sW2     = (const float*)d_in[10];
    const float* sb2     = (const float*)d_in[11];
    float* Y = (float*)d_out;
    const int N = in_sizes[1];

    const int TMAX = (N + 15 * 64 + 63) / 64;     // 64-padded buckets
    const int CAP  = TMAX * 64;

    size_t o = 0;
    auto take = [&](size_t bytes) { size_t r = o; o += (bytes + 255) & ~(size_t)255; return r; };
    char* ws = (char*)d_ws;
    unsigned short* w1bf = (unsigned short*)(ws + take((size_t)8 * HID * IN_F * 2));
    unsigned short* w2bf = (unsigned short*)(ws + take((size_t)8 * OUT_F * HID * 2));
    int*   pid      = (int*)  (ws + take((size_t)N * 4));
    float* gA       = (float*)(ws + take((size_t)N * 4));
    float* gB       = (float*)(ws + take((size_t)N * 4));
    int*   counts   = (int*)  (ws + take(64));
    int*   cursors  = (int*)  (ws + take(64));
    int*   offs     = (int*)  (ws + take(64));
    int*   idxl     = (int*)  (ws + take((size_t)CAP * 4));
    float* gAl      = (float*)(ws + take((size_t)CAP * 4));
    float* gBl      = (float*)(ws + take((size_t)CAP * 4));
    int*   tile_pair= (int*)  (ws + take((size_t)TMAX * 4));

    k_prep<<<8192, 256, 0, stream>>>(rW1, sW1, rW2, sW2, w1bf, w2bf,
                                     counts, cursors, idxl, tile_pair, CAP, TMAX);
    k_router<<<(N + 255) / 256, 256, 0, stream>>>(species, emb, Wr, pid, gA, gB, counts, N);
    k_scan<<<1, 256, 0, stream>>>(counts, offs, tile_pair, TMAX);
    k_scatter<<<(N + 255) / 256, 256, 0, stream>>>(pid, gA, gB, offs, cursors, idxl, gAl, gBl, N);
    k_moe<<<TMAX, 512, 0, stream>>>(X, w1bf, w2bf, idxl, gAl, gBl, tile_pair,
                                    rb1, rb2, sb1, sb2, Y);
}